// Round 6
// baseline (315.587 us; speedup 1.0000x reference)
//
#include <hip/hip_runtime.h>
#include <hip/hip_fp16.h>

// AdultConnectomeNetwork: 3 layers of  x = A @ (W @ x) + bias
// A and W share the same sorted-COO pattern (rows sorted, cols random).
// N=50000, NNZ=800000, B=64, L=3.
//
// R5: clean test of the L2-residency theory. Gather throughput is pinned at
// ~22G 128B-line-touches/s (~27 cyc/line/CU) = per-CU miss-queue x L3-miss
// latency. Fix latency: bin edges by column range (4 bins -> 1.6MB x-slice
// per phase, L2-resident) with BIN-MAJOR CONTIGUOUS edge arrays (sequential
// edge stream per phase, unlike R4's fragmented row-major layout), grid
// fully resident (1536 blocks, launch_bounds(256,6), ~50 VGPR - no spills),
// accumulators in registers across phases.

#define CBINS 4
#define EB 4
#define SCAN_CHUNK 1024
#define SPMM_GRID 1536          // 6 blocks/CU * 256 CUs (launch_bounds(256,6))

__device__ __forceinline__ int bin_of(unsigned int c, unsigned int n) {
    int b = (int)((c * (unsigned int)CBINS) / n);
    return b >= CBINS ? CBINS - 1 : b;
}

__global__ void build_row_ptr_kernel(const int* __restrict__ rows, int nnz,
                                     int n, int* __restrict__ row_ptr) {
    int r = blockIdx.x * blockDim.x + threadIdx.x;
    if (r > n) return;
    int lo = 0, hi = nnz;
    while (lo < hi) {
        int mid = (lo + hi) >> 1;
        if (rows[mid] < r) lo = mid + 1; else hi = mid;
    }
    row_ptr[r] = lo;
}

// k1: per-row, per-bin edge counts.
__global__ void count_bins_kernel(const int* __restrict__ cols,
                                  const int* __restrict__ row_ptr,
                                  int n, int* __restrict__ cnt) {   // [CBINS*n]
    int r = blockIdx.x * blockDim.x + threadIdx.x;
    if (r >= n) return;
    const int e0 = row_ptr[r], e1 = row_ptr[r + 1];
    int k[CBINS];
#pragma unroll
    for (int b = 0; b < CBINS; ++b) k[b] = 0;
    for (int e = e0; e < e1; ++e) k[bin_of((unsigned)cols[e], (unsigned)n)]++;
#pragma unroll
    for (int b = 0; b < CBINS; ++b) cnt[b * n + r] = k[b];
}

// k2a: per-chunk exclusive scan of cnt (chunk = SCAN_CHUNK rows of one bin).
__global__ void scan_chunks_kernel(const int* __restrict__ cnt,  // [CBINS*n]
                                   int* __restrict__ pre,        // [CBINS*n]
                                   int* __restrict__ part,       // [CBINS*nchunk]
                                   int n, int nchunk) {
    const int b = blockIdx.x / nchunk;
    const int chunk = blockIdx.x % nchunk;
    const int base = chunk * SCAN_CHUNK;
    const int t = threadIdx.x;
    __shared__ int ssum[256];

    int local[4], s = 0;
#pragma unroll
    for (int j = 0; j < 4; ++j) {
        int r = base + t * 4 + j;
        int v = (r < n) ? cnt[b * n + r] : 0;
        local[j] = s;
        s += v;
    }
    ssum[t] = s;
    __syncthreads();
    for (int offs = 1; offs < 256; offs <<= 1) {
        int v = (t >= offs) ? ssum[t - offs] : 0;
        __syncthreads();
        ssum[t] += v;
        __syncthreads();
    }
    const int texcl = (t == 0) ? 0 : ssum[t - 1];
    if (t == 255) part[b * nchunk + chunk] = ssum[255];
#pragma unroll
    for (int j = 0; j < 4; ++j) {
        int r = base + t * 4 + j;
        if (r < n) pre[b * n + r] = texcl + local[j];
    }
}

// k2b: single-block exclusive scan of the (bin-major) chunk partials.
__global__ void scan_parts_kernel(int* __restrict__ part, int total) {
    __shared__ int s[256];
    const int t = threadIdx.x;
    int v = (t < total) ? part[t] : 0;
    s[t] = v;
    __syncthreads();
    for (int offs = 1; offs < 256; offs <<= 1) {
        int u = (t >= offs) ? s[t - offs] : 0;
        __syncthreads();
        s[t] += u;
        __syncthreads();
    }
    if (t < total) part[t] = (t == 0) ? 0 : s[t - 1];
}

// k2c: rpb2[b*(n+1)+r] = global start of row r's bin-b segment.
__global__ void finalize_rpb_kernel(const int* __restrict__ pre,
                                    const int* __restrict__ part,
                                    int* __restrict__ rpb2,
                                    int n, int nchunk, int nnz) {
    int i = blockIdx.x * blockDim.x + threadIdx.x;
    const int total = CBINS * (n + 1);
    if (i >= total) return;
    const int b = i / (n + 1);
    const int r = i % (n + 1);
    int v;
    if (r < n) v = part[b * nchunk + r / SCAN_CHUNK] + pre[b * n + r];
    else       v = (b < CBINS - 1) ? part[(b + 1) * nchunk] : nnz;
    rpb2[i] = v;
}

// k3: scatter packed (col,val) edges into bin-major arrays.
__global__ void scatter_edges_kernel(const int* __restrict__ cols,
                                     const float* __restrict__ wv,
                                     const float* __restrict__ av,
                                     const int* __restrict__ row_ptr,
                                     const int* __restrict__ rpb2,
                                     int n,
                                     uint2* __restrict__ pw,
                                     uint2* __restrict__ pa) {
    int r = blockIdx.x * blockDim.x + threadIdx.x;
    if (r >= n) return;
    int cur[CBINS];
#pragma unroll
    for (int b = 0; b < CBINS; ++b) cur[b] = rpb2[b * (n + 1) + r];
    const int e0 = row_ptr[r], e1 = row_ptr[r + 1];
    for (int e = e0; e < e1; ++e) {
        unsigned int c = (unsigned int)cols[e];
        int b = bin_of(c, (unsigned)n);
        int p = cur[b]++;
        uint2 w; w.x = c; w.y = __float_as_uint(wv[e]);
        uint2 a; a.x = c; a.y = __float_as_uint(av[e]);
        pw[p] = w;
        pa[p] = a;
    }
}

// fp32 (N*64) -> fp16 (N*64); one thread per 4 elements.
__global__ void f32_to_f16_kernel(const float4* __restrict__ in,
                                  uint2* __restrict__ out, int n4) {
    int i = blockIdx.x * blockDim.x + threadIdx.x;
    if (i >= n4) return;
    float4 v = in[i];
    __half2 h0 = __floats2half2_rn(v.x, v.y);
    __half2 h1 = __floats2half2_rn(v.z, v.w);
    uint2 r;
    r.x = *(unsigned int*)&h0;
    r.y = *(unsigned int*)&h1;
    out[i] = r;
}

__device__ __forceinline__ void row_phase_acc(const uint2* __restrict__ edges,
                                              const uint2* __restrict__ xin,
                                              int ls, int le, int lane,
                                              float4& acc) {
    for (int e = ls; e < le; e += EB) {
        int   c[EB];
        float v[EB];
#pragma unroll
        for (int j = 0; j < EB; ++j) {
            const int idx = e + j;
            const bool ok = idx < le;
            const uint2 ed = edges[ok ? idx : ls];
            c[j] = ok ? (int)ed.x : 0;
            v[j] = ok ? __uint_as_float(ed.y) : 0.f;
        }
        uint2 raw[EB];
#pragma unroll
        for (int j = 0; j < EB; ++j) {
            raw[j] = xin[c[j] * 16 + lane];   // 8B/lane, 128B/row, 1 line
        }
#pragma unroll
        for (int j = 0; j < EB; ++j) {
            const __half2 h0 = *(const __half2*)&raw[j].x;
            const __half2 h1 = *(const __half2*)&raw[j].y;
            const float2 f0 = __half22float2(h0);
            const float2 f1 = __half22float2(h1);
            acc.x += v[j] * f0.x;
            acc.y += v[j] * f0.y;
            acc.z += v[j] * f1.x;
            acc.w += v[j] * f1.y;
        }
    }
}

// Phase-outer SpMM over bin-major edge arrays. Block owns rows_per_block
// contiguous rows; group g handles local rows g, g+16, g+32 (3 slabs).
template <bool ADD_BIAS, bool OUT_F32>
__global__ __launch_bounds__(256, 6)
void spmm_binned_kernel(const uint2* __restrict__ edges,
                        const int* __restrict__ rpb2,    // [CBINS*(n+1)]
                        const uint2* __restrict__ xin,   // [n*16] fp16x4
                        const float* __restrict__ bias,
                        uint2* __restrict__ y16,
                        float4* __restrict__ y32,
                        int n, int rows_per_block) {
    const int g = threadIdx.x >> 4;
    const int lane = threadIdx.x & 15;
    const int row_base = blockIdx.x * rows_per_block;

    int  rw[3];
    bool ok[3];
#pragma unroll
    for (int s = 0; s < 3; ++s) {
        const int lr = g + 16 * s;
        rw[s] = row_base + lr;
        ok[s] = (lr < rows_per_block) && (rw[s] < n);
    }

    float4 acc[3];
#pragma unroll
    for (int s = 0; s < 3; ++s) acc[s] = make_float4(0.f, 0.f, 0.f, 0.f);

    // All resident blocks sweep bin b together: 1.6MB x-slice + sequential
    // 1.6MB edge stream both L2-resident.
#pragma unroll
    for (int b = 0; b < CBINS; ++b) {
#pragma unroll
        for (int s = 0; s < 3; ++s) {
            if (!ok[s]) continue;
            const int ls = rpb2[b * (n + 1) + rw[s]];
            const int le = rpb2[b * (n + 1) + rw[s] + 1];
            row_phase_acc(edges, xin, ls, le, lane, acc[s]);
        }
    }

#pragma unroll
    for (int s = 0; s < 3; ++s) {
        if (!ok[s]) continue;
        if (ADD_BIAS) {
            const float bb = bias[rw[s]];
            acc[s].x += bb; acc[s].y += bb; acc[s].z += bb; acc[s].w += bb;
        }
        if (OUT_F32) {
            y32[rw[s] * 16 + lane] = acc[s];
        } else {
            __half2 h0 = __floats2half2_rn(acc[s].x, acc[s].y);
            __half2 h1 = __floats2half2_rn(acc[s].z, acc[s].w);
            uint2 r;
            r.x = *(unsigned int*)&h0;
            r.y = *(unsigned int*)&h1;
            y16[rw[s] * 16 + lane] = r;
        }
    }
}

extern "C" void kernel_launch(void* const* d_in, const int* in_sizes, int n_in,
                              void* d_out, int out_size, void* d_ws, size_t ws_size,
                              hipStream_t stream) {
    const float* x_in     = (const float*)d_in[0];  // (N, 64)
    const float* adj_vals = (const float*)d_in[1];  // (NNZ,)
    const float* w_vals   = (const float*)d_in[2];  // (NNZ,)
    const float* bias     = (const float*)d_in[3];  // (N,)
    const int*   rows     = (const int*)d_in[4];    // (NNZ,) sorted
    const int*   cols     = (const int*)d_in[5];    // (NNZ,)
    // d_in[6] = n_layers (device scalar); structurally 3.

    const int N   = in_sizes[3];
    const int NNZ = in_sizes[1];
    const int nchunk = (N + SCAN_CHUNK - 1) / SCAN_CHUNK;   // 49 for N=50000

    // Workspace: row_ptr | cnt | pre | part | rpb2 | xh | yh | pw | pa
    char* ws = (char*)d_ws;
    size_t off = 0;
    int* row_ptr = (int*)(ws + off);
    off += ((size_t)(N + 1) * 4 + 255) & ~(size_t)255;
    int* cnt = (int*)(ws + off);
    off += ((size_t)CBINS * N * 4 + 255) & ~(size_t)255;
    int* pre = (int*)(ws + off);
    off += ((size_t)CBINS * N * 4 + 255) & ~(size_t)255;
    int* part = (int*)(ws + off);
    off += ((size_t)CBINS * nchunk * 4 + 255) & ~(size_t)255;
    int* rpb2 = (int*)(ws + off);
    off += ((size_t)CBINS * (N + 1) * 4 + 255) & ~(size_t)255;
    uint2* xh = (uint2*)(ws + off);  off += (size_t)N * 16 * 8;
    uint2* yh = (uint2*)(ws + off);  off += (size_t)N * 16 * 8;
    uint2* pw = (uint2*)(ws + off);  off += (size_t)NNZ * 8;
    uint2* pa = (uint2*)(ws + off);

    // --- prep (amortized over 6 SpMMs) ---
    build_row_ptr_kernel<<<(N + 256) / 256, 256, 0, stream>>>(rows, NNZ, N, row_ptr);
    count_bins_kernel<<<(N + 255) / 256, 256, 0, stream>>>(cols, row_ptr, N, cnt);
    scan_chunks_kernel<<<CBINS * nchunk, 256, 0, stream>>>(cnt, pre, part, N, nchunk);
    scan_parts_kernel<<<1, 256, 0, stream>>>(part, CBINS * nchunk);
    finalize_rpb_kernel<<<(CBINS * (N + 1) + 255) / 256, 256, 0, stream>>>(pre, part, rpb2, N, nchunk, NNZ);
    scatter_edges_kernel<<<(N + 255) / 256, 256, 0, stream>>>(cols, w_vals, adj_vals,
                                                              row_ptr, rpb2, N, pw, pa);
    f32_to_f16_kernel<<<(N * 16 + 255) / 256, 256, 0, stream>>>((const float4*)x_in, xh, N * 16);

    // --- 6 SpMMs ---
    const int rows_per_block = (N + SPMM_GRID - 1) / SPMM_GRID;   // 33
    float4* out32 = (float4*)d_out;

    spmm_binned_kernel<false, false><<<SPMM_GRID, 256, 0, stream>>>(pw, rpb2, xh, nullptr, yh, nullptr, N, rows_per_block);
    spmm_binned_kernel<true,  false><<<SPMM_GRID, 256, 0, stream>>>(pa, rpb2, yh, bias, xh, nullptr, N, rows_per_block);
    spmm_binned_kernel<false, false><<<SPMM_GRID, 256, 0, stream>>>(pw, rpb2, xh, nullptr, yh, nullptr, N, rows_per_block);
    spmm_binned_kernel<true,  false><<<SPMM_GRID, 256, 0, stream>>>(pa, rpb2, yh, bias, xh, nullptr, N, rows_per_block);
    spmm_binned_kernel<false, false><<<SPMM_GRID, 256, 0, stream>>>(pw, rpb2, xh, nullptr, yh, nullptr, N, rows_per_block);
    spmm_binned_kernel<true,  true ><<<SPMM_GRID, 256, 0, stream>>>(pa, rpb2, yh, bias, nullptr, out32, N, rows_per_block);
}

// Round 7
// 230.749 us; speedup vs baseline: 1.3677x; 1.3677x over previous
//
#include <hip/hip_runtime.h>
#include <hip/hip_fp16.h>

// AdultConnectomeNetwork: 3 layers of  x = A @ (W @ x) + bias
// A and W share the same sorted-COO pattern (rows sorted, cols random).
// N=50000, NNZ=800000, B=64, L=3.
//
// R6: binning/locality falsified (R4/R5 regressed). The floor is the per-CU
// miss-queue x latency product on divergent gathers. Discriminating test:
// wave-per-row layout -> ONE gather instruction covers 8 edges (8 octets x
// 16B uint4 lanes = 8 full 128B fp16 rows), halving divergent instruction
// count and lanes/edge at constant line-touches. Edge metadata is read as
// 8 consecutive edges per wave (contiguous, 1 touch). Cross-octet reduction
// via 24 shfl_xor per row. No binning, no perm, no LDS.

__global__ void build_row_ptr_kernel(const int* __restrict__ rows, int nnz,
                                     int n, int* __restrict__ row_ptr) {
    int r = blockIdx.x * blockDim.x + threadIdx.x;
    if (r > n) return;
    int lo = 0, hi = nnz;
    while (lo < hi) {
        int mid = (lo + hi) >> 1;
        if (rows[mid] < r) lo = mid + 1; else hi = mid;
    }
    row_ptr[r] = lo;
}

// Pack (col, val) pairs for both matrices in one pass (CSR order).
__global__ void pack_edges_kernel(const int* __restrict__ cols,
                                  const float* __restrict__ wv,
                                  const float* __restrict__ av,
                                  uint2* __restrict__ pw,
                                  uint2* __restrict__ pa, int nnz) {
    int i = blockIdx.x * blockDim.x + threadIdx.x;
    if (i >= nnz) return;
    unsigned int c = (unsigned int)cols[i];
    uint2 w; w.x = c; w.y = __float_as_uint(wv[i]);
    uint2 a; a.x = c; a.y = __float_as_uint(av[i]);
    pw[i] = w;
    pa[i] = a;
}

// fp32 (N*64) -> fp16 (N*64); one thread per 4 elements.
__global__ void f32_to_f16_kernel(const float4* __restrict__ in,
                                  uint2* __restrict__ out, int n4) {
    int i = blockIdx.x * blockDim.x + threadIdx.x;
    if (i >= n4) return;
    float4 v = in[i];
    __half2 h0 = __floats2half2_rn(v.x, v.y);
    __half2 h1 = __floats2half2_rn(v.z, v.w);
    uint2 r;
    r.x = *(unsigned int*)&h0;
    r.y = *(unsigned int*)&h1;
    out[i] = r;
}

// One wave per row. Octet o (lanes o*8..o*8+7) handles edge e+o; sublane l
// owns columns [8l, 8l+8) as one uint4 (8 halves). One gather instruction
// per 8 edges. After the loop, reduce partial sums across octets (shfl_xor
// 8/16/32), then lanes 0..7 add bias and store the 128B row.
template <bool ADD_BIAS, bool OUT_F32>
__global__ void spmm_waverow_kernel(const uint2* __restrict__ edges,
                                    const int* __restrict__ row_ptr,
                                    const uint4* __restrict__ xin,   // [n*8] fp16x8
                                    const float* __restrict__ bias,
                                    uint4* __restrict__ y16,         // [n*8] fp16x8
                                    float4* __restrict__ y32,        // [n*16] fp32x4
                                    int n) {
    const int row = blockIdx.x * 4 + (threadIdx.x >> 6);   // 4 waves/block
    if (row >= n) return;
    const int o = (threadIdx.x >> 3) & 7;                  // octet within wave
    const int l = threadIdx.x & 7;                         // sublane within octet

    const int e0 = row_ptr[row];
    const int e1 = row_ptr[row + 1];

    float acc[8];
#pragma unroll
    for (int q = 0; q < 8; ++q) acc[q] = 0.f;

    for (int e = e0; e < e1; e += 8) {
        const int idx = e + o;
        const bool ok = idx < e1;
        const uint2 ed = edges[ok ? idx : e0];     // 8 consecutive edges/wave
        const int   c  = ok ? (int)ed.x : 0;
        const float v  = ok ? __uint_as_float(ed.y) : 0.f;
        const uint4 raw = xin[c * 8 + l];          // 16B/lane, 8 rows/instr
        const __half2* h = (const __half2*)&raw;
#pragma unroll
        for (int q = 0; q < 4; ++q) {
            const float2 f = __half22float2(h[q]);
            acc[2 * q]     += v * f.x;
            acc[2 * q + 1] += v * f.y;
        }
    }

    // Reduce across octets: lanes {o*8+l | o=0..7} all hold column slice l.
#pragma unroll
    for (int off = 8; off < 64; off <<= 1) {
#pragma unroll
        for (int q = 0; q < 8; ++q) acc[q] += __shfl_xor(acc[q], off, 64);
    }

    if ((threadIdx.x & 63) < 8) {   // lanes 0..7 hold the full row sum
        if (ADD_BIAS) {
            const float b = bias[row];
#pragma unroll
            for (int q = 0; q < 8; ++q) acc[q] += b;
        }
        if (OUT_F32) {
            float4 f0 = make_float4(acc[0], acc[1], acc[2], acc[3]);
            float4 f1 = make_float4(acc[4], acc[5], acc[6], acc[7]);
            y32[row * 16 + 2 * l]     = f0;
            y32[row * 16 + 2 * l + 1] = f1;
        } else {
            __half2 h0 = __floats2half2_rn(acc[0], acc[1]);
            __half2 h1 = __floats2half2_rn(acc[2], acc[3]);
            __half2 h2 = __floats2half2_rn(acc[4], acc[5]);
            __half2 h3 = __floats2half2_rn(acc[6], acc[7]);
            uint4 r;
            r.x = *(unsigned int*)&h0;
            r.y = *(unsigned int*)&h1;
            r.z = *(unsigned int*)&h2;
            r.w = *(unsigned int*)&h3;
            y16[row * 8 + l] = r;
        }
    }
}

extern "C" void kernel_launch(void* const* d_in, const int* in_sizes, int n_in,
                              void* d_out, int out_size, void* d_ws, size_t ws_size,
                              hipStream_t stream) {
    const float* x_in     = (const float*)d_in[0];  // (N, 64)
    const float* adj_vals = (const float*)d_in[1];  // (NNZ,)
    const float* w_vals   = (const float*)d_in[2];  // (NNZ,)
    const float* bias     = (const float*)d_in[3];  // (N,)
    const int*   rows     = (const int*)d_in[4];    // (NNZ,) sorted
    const int*   cols     = (const int*)d_in[5];    // (NNZ,)
    // d_in[6] = n_layers (device scalar); structurally 3.

    const int N   = in_sizes[3];
    const int NNZ = in_sizes[1];

    // Workspace: row_ptr | xh | yh | pw | pa
    char* ws = (char*)d_ws;
    size_t off = 0;
    int* row_ptr = (int*)(ws + off);
    off += ((size_t)(N + 1) * 4 + 255) & ~(size_t)255;
    uint4* xh = (uint4*)(ws + off);  off += (size_t)N * 8 * 16;   // N*64 halves
    uint4* yh = (uint4*)(ws + off);  off += (size_t)N * 8 * 16;
    uint2* pw = (uint2*)(ws + off);  off += (size_t)NNZ * 8;
    uint2* pa = (uint2*)(ws + off);

    // --- prep ---
    build_row_ptr_kernel<<<(N + 256) / 256, 256, 0, stream>>>(rows, NNZ, N, row_ptr);
    pack_edges_kernel<<<(NNZ + 255) / 256, 256, 0, stream>>>(cols, w_vals, adj_vals, pw, pa, NNZ);
    f32_to_f16_kernel<<<(N * 16 + 255) / 256, 256, 0, stream>>>((const float4*)x_in,
                                                                (uint2*)xh, N * 16);

    // --- 6 SpMMs: one wave per row, 4 waves per block ---
    const int blocks = (N + 3) / 4;
    float4* out32 = (float4*)d_out;

    spmm_waverow_kernel<false, false><<<blocks, 256, 0, stream>>>(pw, row_ptr, xh, nullptr, yh, nullptr, N);
    spmm_waverow_kernel<true,  false><<<blocks, 256, 0, stream>>>(pa, row_ptr, yh, bias, xh, nullptr, N);
    spmm_waverow_kernel<false, false><<<blocks, 256, 0, stream>>>(pw, row_ptr, xh, nullptr, yh, nullptr, N);
    spmm_waverow_kernel<true,  false><<<blocks, 256, 0, stream>>>(pa, row_ptr, yh, bias, xh, nullptr, N);
    spmm_waverow_kernel<false, false><<<blocks, 256, 0, stream>>>(pw, row_ptr, xh, nullptr, yh, nullptr, N);
    spmm_waverow_kernel<true,  true ><<<blocks, 256, 0, stream>>>(pa, row_ptr, yh, bias, nullptr, out32, N);
}